// Round 5
// baseline (6292.881 us; speedup 1.0000x reference)
//
#include <hip/hip_runtime.h>

typedef unsigned short u16;
typedef unsigned int u32;
typedef __attribute__((ext_vector_type(8))) short bf16x8;   // 8 x bf16 (4 VGPRs)
typedef __attribute__((ext_vector_type(4))) float f32x4;

#define MFMA16(a, b, c) __builtin_amdgcn_mfma_f32_16x16x32_bf16((a), (b), (c), 0, 0, 0)

__device__ __forceinline__ u16 f2bf(float f) {
  union { float f; unsigned u; } v; v.f = f;
  unsigned r = v.u + 0x7FFF + ((v.u >> 16) & 1);   // round-to-nearest-even
  return (u16)(r >> 16);
}
__device__ __forceinline__ float bf2f(u16 h) {
  union { unsigned u; float f; } v; v.u = ((unsigned)h) << 16;
  return v.f;
}

// Agent-coherent (sc1) 8x16B load of one wave's h slice + in-asm drain.
// sc1 = agent scope on gfx950: bypasses the (non-cross-XCD-coherent) L2,
// served by the coherent Infinity Cache.
__device__ __forceinline__ void load_h8_sc1(const u16* p, bf16x8* a) {
  asm volatile(
      "global_load_dwordx4 %0, %8, off sc1\n\t"
      "global_load_dwordx4 %1, %8, off offset:64 sc1\n\t"
      "global_load_dwordx4 %2, %8, off offset:128 sc1\n\t"
      "global_load_dwordx4 %3, %8, off offset:192 sc1\n\t"
      "global_load_dwordx4 %4, %8, off offset:256 sc1\n\t"
      "global_load_dwordx4 %5, %8, off offset:320 sc1\n\t"
      "global_load_dwordx4 %6, %8, off offset:384 sc1\n\t"
      "global_load_dwordx4 %7, %8, off offset:448 sc1\n\t"
      "s_waitcnt vmcnt(0)"
      : "=&v"(a[0]), "=&v"(a[1]), "=&v"(a[2]), "=&v"(a[3]),
        "=&v"(a[4]), "=&v"(a[5]), "=&v"(a[6]), "=&v"(a[7])
      : "v"(p)
      : "memory");
}

__device__ __forceinline__ void store_h_sc1(u16* p, u32 v) {
  asm volatile("global_store_short %0, %1, off sc1" :: "v"(p), "v"(v) : "memory");
}

// ---------- zero barrier state: 32 lines of 64 u32 (256B apart) ----------
__global__ void k_zero(u32* p) {
  p[(blockIdx.x * 256 + threadIdx.x)] = 0;   // <<<8,256>>> zeros 2048 u32 = 8KB
}

// ---------- f32 -> bf16 bulk convert (n multiple of 8) ----------
__global__ void k_convert(const float* __restrict__ src, u16* __restrict__ dst, int n8) {
  int i = blockIdx.x * 256 + threadIdx.x;
  if (i >= n8) return;
  const float4* s = (const float4*)src + (size_t)i * 2;
  float4 a = s[0], b = s[1];
  u16 o[8] = { f2bf(a.x), f2bf(a.y), f2bf(a.z), f2bf(a.w),
               f2bf(b.x), f2bf(b.y), f2bf(b.z), f2bf(b.w) };
  *(bf16x8*)(dst + (size_t)i * 8) = *(bf16x8*)o;
}

// ---------- embedding gather -> A0 bf16, row i = t*64 + b ----------
__global__ void k_gather(const int* __restrict__ x, const float* __restrict__ emb,
                         u16* __restrict__ A0) {
  int gid = blockIdx.x * 256 + threadIdx.x;   // 32768 rows * 128 thr/row
  int row = gid >> 7;
  int e = (gid & 127) << 3;
  int t = row >> 6, b = row & 63;
  int v = x[b * 512 + t];
  const float4* s = (const float4*)(emb + (size_t)v * 1024 + e);
  float4 a = s[0], c = s[1];
  u16 o[8] = { f2bf(a.x), f2bf(a.y), f2bf(a.z), f2bf(a.w),
               f2bf(c.x), f2bf(c.y), f2bf(c.z), f2bf(c.w) };
  *(bf16x8*)(A0 + (size_t)row * 1024 + e) = *(bf16x8*)o;
}

// ---------- h0 init: bf16 copy (65536 elems) ----------
__global__ void k_hinit(const float* __restrict__ h0l, u16* __restrict__ hbf) {
  int i = blockIdx.x * 256 + threadIdx.x;
  hbf[i] = f2bf(h0l[i]);
}

// ---------- big GEMM: C[M=32768][3072] = A[M][1024] @ W[3072][1024]^T + bias ----------
// 128x128 tile, 4 waves (2x2), each wave 64x64 = 4x4 frags of 16x16x32.
__global__ __launch_bounds__(256) void k_gemm(const u16* __restrict__ A,
                                              const u16* __restrict__ W,
                                              const float* __restrict__ bias,
                                              u16* __restrict__ C) {
  __shared__ __attribute__((aligned(16))) u16 As[128 * 40];
  __shared__ __attribute__((aligned(16))) u16 Bs[128 * 40];
  int tid = threadIdx.x;
  int m0 = blockIdx.x * 128;
  int n0 = blockIdx.y * 128;
  int lane = tid & 63, wave = tid >> 6;
  int quad = lane >> 4, l15 = lane & 15;
  int wm = (wave >> 1) * 64, wn = (wave & 1) * 64;
  f32x4 acc[4][4] = {};
  for (int kc = 0; kc < 1024; kc += 32) {
#pragma unroll
    for (int i = 0; i < 2; i++) {
      int g = tid + i * 256;            // 0..511: row = g/4, kg = (g%4)*8
      int row = g >> 2, kg = (g & 3) << 3;
      *(bf16x8*)(As + row * 40 + kg) = *(const bf16x8*)(A + (size_t)(m0 + row) * 1024 + kc + kg);
      *(bf16x8*)(Bs + row * 40 + kg) = *(const bf16x8*)(W + (size_t)(n0 + row) * 1024 + kc + kg);
    }
    __syncthreads();
    bf16x8 af[4], bf[4];
#pragma unroll
    for (int mi = 0; mi < 4; mi++)
      af[mi] = *(const bf16x8*)(As + (wm + mi * 16 + l15) * 40 + quad * 8);
#pragma unroll
    for (int ni = 0; ni < 4; ni++)
      bf[ni] = *(const bf16x8*)(Bs + (wn + ni * 16 + l15) * 40 + quad * 8);
#pragma unroll
    for (int mi = 0; mi < 4; mi++)
#pragma unroll
      for (int ni = 0; ni < 4; ni++)
        acc[mi][ni] = MFMA16(af[mi], bf[ni], acc[mi][ni]);
    __syncthreads();
  }
  // C/D layout: n = lane&15 (+tile), m = quad*4 + reg (+tile)
#pragma unroll
  for (int mi = 0; mi < 4; mi++)
#pragma unroll
    for (int ni = 0; ni < 4; ni++)
#pragma unroll
      for (int r = 0; r < 4; r++) {
        int m = m0 + wm + mi * 16 + quad * 4 + r;
        int n = n0 + wn + ni * 16 + l15;
        C[(size_t)m * 3072 + n] = f2bf(acc[mi][ni][r] + bias[n]);
      }
}

// ---------- persistent GRU step kernel: all 512 timesteps, one launch ----------
// Cooperative launch, EXACTLY 256 blocks x 256 threads.
// Block = (j-group = bid>>2, mtile = bid&3). 4 waves each compute one K-quarter
// of the 3 gate matvecs; partials reduced via LDS (1 syncthreads/step); wave 0
// runs the epilogue. Whh slice (48x1024) staged in LDS once. f32 h state in
// wave-0 registers. bf16 h circulates via sc1 (agent-coherent) loads/stores ->
// no cache-maintenance fences. Sync: 4 INDEPENDENT per-mtile barriers
// (monotonic counters, 8 lines x 8 arrivals each); single-stage — every wave
// polls its mtile's 8 lines directly and self-releases.
// Ordering proof sketch:
//   - waves 1..3 exit the step-t poll only after ALL 64 same-mtile blocks
//     arrived, incl. own block's wave 0; wave 0 arrives only after it has
//     consumed Red(t) and drained its sc1 h stores => Red(t+1) writes can't
//     race Red(t) reads, and h(t) is MALL-visible before any consumer load.
//   - double-buffer WAR (layer 1): writing h(t+1) needs passing barrier t,
//     which needs every consumer's arrival t, which is after their h(t-1)
//     reads; buffers alternate t-parity => >=1-step separation. Layer 0
//     writes distinct per-t slices (no reuse).
__global__ __launch_bounds__(256) void k_steps(
    const u16* __restrict__ Whh, const float* __restrict__ bhh,
    const u16* __restrict__ gx, const float* __restrict__ h0l,
    const u16* __restrict__ hbf_init,
    u16* __restrict__ states,            // non-null (layer0): read t-1 / write t at states + t*65536
    u16* __restrict__ bufA, u16* __restrict__ bufB,   // layer1 double-buffer
    float* __restrict__ hiddens,         // layer0: [b][t][1024] f32 out, else null
    float* __restrict__ hfinal,          // [64][1024] final h (t=511)
    float* __restrict__ out2,            // optional second copy of final h
    u32* __restrict__ bar) {             // 32 lines: line L at bar[L*64]; L = mtile*8 + (jg&7)
  __shared__ __attribute__((aligned(16))) u16 Bs[48 * 1032];     // pad 1024->1032
  __shared__ __attribute__((aligned(16))) float Red[2304];       // [3 waves][3 gates][64 lanes] f32x4
  int tid = threadIdx.x;
  int lane = tid & 63, wave = tid >> 6;          // wave 0..3 = K-quarter
  int quad = lane >> 4, l15 = lane & 15;
  int bid = (int)blockIdx.x;
  int jg = bid >> 2;
  int mtile = bid & 3;
  int j0 = jg * 16;
  int j = j0 + l15;
  int kbase = wave * 256;
  u32* myline = bar + (mtile * 8 + (jg & 7)) * 64;     // this block's arrival line

  // ---- stage Whh slice: rows (gate*16 + jr), full K=1024
#pragma unroll 4
  for (int i = 0; i < 24; i++) {
    int g = tid + i * 256;                 // row = g>>7, kg = (g&127)*8
    int row = g >> 7, kg = (g & 127) << 3;
    int gate = row >> 4, jr = row & 15;
    *(bf16x8*)(Bs + row * 1032 + kg) =
        *(const bf16x8*)(Whh + (size_t)(gate * 1024 + j0 + jr) * 1024 + kg);
  }

  float br = 0.f, bz = 0.f, bn = 0.f;
  float hold[4] = {};
  u16 gvn[3][4];
  if (wave == 0) {
    br = bhh[j]; bz = bhh[1024 + j]; bn = bhh[2048 + j];
#pragma unroll
    for (int r = 0; r < 4; r++)
      hold[r] = h0l[(mtile * 16 + quad * 4 + r) * 1024 + j];
#pragma unroll
    for (int g = 0; g < 3; g++)
#pragma unroll
      for (int r = 0; r < 4; r++)
        gvn[g][r] = gx[(mtile * 16 + quad * 4 + r) * 3072 + g * 1024 + j];   // t=0
  }
  __syncthreads();

  for (int t = 0; t < 512; t++) {
    const u16* hin = (t == 0) ? hbf_init
                   : (states ? states + (size_t)(t - 1) * 65536
                             : ((t & 1) ? bufB : bufA));
    u16* hout = states ? states + (size_t)t * 65536 : ((t & 1) ? bufA : bufB);

    // coherent h load (self-draining asm) then MFMA over this wave's K-quarter
    bf16x8 a[8];
    load_h8_sc1(hin + (size_t)(mtile * 16 + l15) * 1024 + kbase + quad * 8, a);
    f32x4 acc[3] = {};
#pragma unroll
    for (int kk = 0; kk < 8; kk++) {
#pragma unroll
      for (int g = 0; g < 3; g++) {
        bf16x8 b = *(const bf16x8*)(Bs + (g * 16 + l15) * 1032 + kbase + kk * 32 + quad * 8);
        acc[g] = MFMA16(a[kk], b, acc[g]);
      }
    }
    if (wave) {
#pragma unroll
      for (int g = 0; g < 3; g++)
        *(f32x4*)(Red + (((wave - 1) * 3 + g) * 64 + lane) * 4) = acc[g];
    }
    __syncthreads();   // Red(t) ready (the only block-wide sync per step)

    if (wave == 0) {
#pragma unroll
      for (int g = 0; g < 3; g++) {
        acc[g] += *(const f32x4*)(Red + ((0 * 3 + g) * 64 + lane) * 4);
        acc[g] += *(const f32x4*)(Red + ((1 * 3 + g) * 64 + lane) * 4);
        acc[g] += *(const f32x4*)(Red + ((2 * 3 + g) * 64 + lane) * 4);
      }
#pragma unroll
      for (int r = 0; r < 4; r++) {
        int m = mtile * 16 + quad * 4 + r;
        float xr = bf2f(gvn[0][r]);
        float xz = bf2f(gvn[1][r]);
        float xn = bf2f(gvn[2][r]);
        float rg = 1.f / (1.f + __expf(-(xr + acc[0][r] + br)));
        float zg = 1.f / (1.f + __expf(-(xz + acc[1][r] + bz)));
        float nx = xn + rg * (acc[2][r] + bn);
        nx = fminf(15.f, fmaxf(-15.f, nx));
        float e2 = __expf(2.f * nx);
        float ng = (e2 - 1.f) / (e2 + 1.f);
        float hnew = (1.f - zg) * ng + zg * hold[r];
        hold[r] = hnew;
        store_h_sc1(hout + m * 1024 + j, (u32)f2bf(hnew));
      }
      // drain ONLY the 4 sc1 h stores (hiddens deferred past arrival)
      asm volatile("s_waitcnt vmcnt(0)" ::: "memory");

      // arrival: relaxed RMW on this block's line (8 arrivals/line, monotonic)
      if (tid == 0 && t < 511)
        __hip_atomic_fetch_add(myline, 1u, __ATOMIC_RELAXED, __HIP_MEMORY_SCOPE_AGENT);

      // deferred, fire-and-forget: hiddens + final outputs + next-gx prefetch
      if (t < 511) {
        const u16* gxn = gx + (size_t)(t + 1) * 196608;
#pragma unroll
        for (int g = 0; g < 3; g++)
#pragma unroll
          for (int r = 0; r < 4; r++)
            gvn[g][r] = gxn[(mtile * 16 + quad * 4 + r) * 3072 + g * 1024 + j];
      }
      if (hiddens) {
#pragma unroll
        for (int r = 0; r < 4; r++) {
          int m = mtile * 16 + quad * 4 + r;
          __builtin_nontemporal_store(hold[r], hiddens + (size_t)m * 524288 + t * 1024 + j);
        }
      }
      if (t == 511) {
#pragma unroll
        for (int r = 0; r < 4; r++) {
          int m = mtile * 16 + quad * 4 + r;
          hfinal[m * 1024 + j] = hold[r];
          if (out2) out2[m * 1024 + j] = hold[r];
        }
      }
    }

    // single-stage poll: every wave checks its mtile's 8 lines, self-releases
    if (t < 511) {
      if (lane < 8) {
        u32 tgt = 8u * (u32)(t + 1);
        const u32* cl = bar + (mtile * 8 + lane) * 64;
        while (__hip_atomic_load(cl, __ATOMIC_RELAXED, __HIP_MEMORY_SCOPE_AGENT) < tgt)
          __builtin_amdgcn_s_sleep(1);
      }
    }
  }
}

extern "C" void kernel_launch(void* const* d_in, const int* in_sizes, int n_in,
                              void* d_out, int out_size, void* d_ws, size_t ws_size,
                              hipStream_t stream) {
  const int*   x   = (const int*)d_in[0];
  const float* h0  = (const float*)d_in[1];
  const float* emb = (const float*)d_in[2];
  const float* Wih = (const float*)d_in[3];
  const float* Whh = (const float*)d_in[4];
  const float* bih = (const float*)d_in[5];
  const float* bhh = (const float*)d_in[6];
  float* out = (float*)d_out;

  // workspace layout (total ~362 MB)
  char* ws = (char*)d_ws;
  u16* WihB = (u16*)ws;  ws += 12582912;            // [2][3072][1024] bf16
  u16* WhhB = (u16*)ws;  ws += 12582912;            // [2][3072][1024] bf16
  u16* A0   = (u16*)ws;  ws += 67108864;            // [32768][1024] bf16 (emb rows, t-major)
  u16* A1   = (u16*)ws;  ws += 67108864;            // [32768][1024] bf16 (layer-0 states)
  u16* gx   = (u16*)ws;  ws += 201326592;           // [32768][3072] bf16 (reused layer0/layer1)
  u16* h0bf = (u16*)ws;  ws += 262144;              // bf16 h0, both layers (2*65536 u16)
  u32* bar  = (u32*)ws;  ws += 262144;              // grid-barrier state (32 lines x 256B)
  u16* hbfA = (u16*)ws;  ws += 131072;              // layer-1 bf16 h double-buffer
  u16* hbfB = (u16*)ws;  ws += 131072;

  float* out_out = out;                 // [1,64,1024]
  float* hidden0 = out + 65536;         // [64,1024]
  float* hidden1 = out + 131072;        // [64,1024]
  float* hiddens = out + 196608;        // [64][512][1024]

  // per-layer stride for [L][3072][1024] weights = 3072*1024 elements
  const size_t WSTRIDE = 3145728;

  k_zero<<<8, 256, 0, stream>>>(bar);
  k_convert<<<3072, 256, 0, stream>>>(Wih, WihB, 786432);  // 6291456/8
  k_convert<<<3072, 256, 0, stream>>>(Whh, WhhB, 786432);
  k_gather<<<16384, 256, 0, stream>>>(x, emb, A0);
  k_hinit<<<256, 256, 0, stream>>>(h0, h0bf);
  k_hinit<<<256, 256, 0, stream>>>(h0 + 65536, h0bf + 65536);

  dim3 ggrid(256, 24);
  k_gemm<<<ggrid, 256, 0, stream>>>(A0, WihB, bih, gx);

  {  // layer 0: all 512 steps, one cooperative launch
    const u16*  p0 = WhhB;
    const float* p1 = bhh;
    const u16*  p2 = gx;
    const float* p3 = h0;
    const u16*  p4 = h0bf;
    u16* p5 = A1;
    u16* p6 = hbfA; u16* p7 = hbfB;
    float* p8 = hiddens; float* p9 = hidden0; float* p10 = nullptr;
    u32* p11 = bar;
    void* args[] = {&p0,&p1,&p2,&p3,&p4,&p5,&p6,&p7,&p8,&p9,&p10,&p11};
    hipLaunchCooperativeKernel((const void*)k_steps, dim3(256), dim3(256), args, 0, stream);
  }

  k_gemm<<<ggrid, 256, 0, stream>>>(A1, WihB + WSTRIDE, bih + 3072, gx);
  k_zero<<<8, 256, 0, stream>>>(bar);   // reset monotonic counters for layer 1

  {  // layer 1
    const u16*  p0 = WhhB + WSTRIDE;
    const float* p1 = bhh + 3072;
    const u16*  p2 = gx;
    const float* p3 = h0 + 65536;
    const u16*  p4 = h0bf + 65536;
    u16* p5 = nullptr;
    u16* p6 = hbfA; u16* p7 = hbfB;
    float* p8 = nullptr; float* p9 = hidden1; float* p10 = out_out;
    u32* p11 = bar;
    void* args[] = {&p0,&p1,&p2,&p3,&p4,&p5,&p6,&p7,&p8,&p9,&p10,&p11};
    hipLaunchCooperativeKernel((const void*)k_steps, dim3(256), dim3(256), args, 0, stream);
  }
}

// Round 6
// 5593.238 us; speedup vs baseline: 1.1251x; 1.1251x over previous
//
#include <hip/hip_runtime.h>

typedef unsigned short u16;
typedef unsigned int u32;
typedef __attribute__((ext_vector_type(8))) short bf16x8;   // 8 x bf16 (4 VGPRs)
typedef __attribute__((ext_vector_type(4))) float f32x4;

#define MFMA16(a, b, c) __builtin_amdgcn_mfma_f32_16x16x32_bf16((a), (b), (c), 0, 0, 0)

__device__ __forceinline__ u16 f2bf(float f) {
  union { float f; unsigned u; } v; v.f = f;
  unsigned r = v.u + 0x7FFF + ((v.u >> 16) & 1);   // round-to-nearest-even
  return (u16)(r >> 16);
}
__device__ __forceinline__ float bf2f(u16 h) {
  union { unsigned u; float f; } v; v.u = ((unsigned)h) << 16;
  return v.f;
}

// Agent-coherent (sc1) 8x16B load of one wave's h slice + in-asm drain.
// sc1 = agent scope on gfx950: bypasses the (non-cross-XCD-coherent) L2,
// served by the coherent Infinity Cache.
__device__ __forceinline__ void load_h8_sc1(const u16* p, bf16x8* a) {
  asm volatile(
      "global_load_dwordx4 %0, %8, off sc1\n\t"
      "global_load_dwordx4 %1, %8, off offset:64 sc1\n\t"
      "global_load_dwordx4 %2, %8, off offset:128 sc1\n\t"
      "global_load_dwordx4 %3, %8, off offset:192 sc1\n\t"
      "global_load_dwordx4 %4, %8, off offset:256 sc1\n\t"
      "global_load_dwordx4 %5, %8, off offset:320 sc1\n\t"
      "global_load_dwordx4 %6, %8, off offset:384 sc1\n\t"
      "global_load_dwordx4 %7, %8, off offset:448 sc1\n\t"
      "s_waitcnt vmcnt(0)"
      : "=&v"(a[0]), "=&v"(a[1]), "=&v"(a[2]), "=&v"(a[3]),
        "=&v"(a[4]), "=&v"(a[5]), "=&v"(a[6]), "=&v"(a[7])
      : "v"(p)
      : "memory");
}

__device__ __forceinline__ void store_h_sc1(u16* p, u32 v) {
  asm volatile("global_store_short %0, %1, off sc1" :: "v"(p), "v"(v) : "memory");
}

// ---------- zero barrier state ----------
__global__ void k_zero(u32* p) {
  p[(blockIdx.x * 256 + threadIdx.x)] = 0;   // <<<8,256>>> zeros 2048 u32 = 8KB
}

// ---------- f32 -> bf16 bulk convert (n multiple of 8) ----------
__global__ void k_convert(const float* __restrict__ src, u16* __restrict__ dst, int n8) {
  int i = blockIdx.x * 256 + threadIdx.x;
  if (i >= n8) return;
  const float4* s = (const float4*)src + (size_t)i * 2;
  float4 a = s[0], b = s[1];
  u16 o[8] = { f2bf(a.x), f2bf(a.y), f2bf(a.z), f2bf(a.w),
               f2bf(b.x), f2bf(b.y), f2bf(b.z), f2bf(b.w) };
  *(bf16x8*)(dst + (size_t)i * 8) = *(bf16x8*)o;
}

// ---------- embedding gather -> A0 bf16, row i = t*64 + b ----------
__global__ void k_gather(const int* __restrict__ x, const float* __restrict__ emb,
                         u16* __restrict__ A0) {
  int gid = blockIdx.x * 256 + threadIdx.x;   // 32768 rows * 128 thr/row
  int row = gid >> 7;
  int e = (gid & 127) << 3;
  int t = row >> 6, b = row & 63;
  int v = x[b * 512 + t];
  const float4* s = (const float4*)(emb + (size_t)v * 1024 + e);
  float4 a = s[0], c = s[1];
  u16 o[8] = { f2bf(a.x), f2bf(a.y), f2bf(a.z), f2bf(a.w),
               f2bf(c.x), f2bf(c.y), f2bf(c.z), f2bf(c.w) };
  *(bf16x8*)(A0 + (size_t)row * 1024 + e) = *(bf16x8*)o;
}

// ---------- h0 init: bf16 copy (65536 elems) ----------
__global__ void k_hinit(const float* __restrict__ h0l, u16* __restrict__ hbf) {
  int i = blockIdx.x * 256 + threadIdx.x;
  hbf[i] = f2bf(h0l[i]);
}

// ---------- big GEMM: C[M=32768][3072] = A[M][1024] @ W[3072][1024]^T + bias ----------
// 128x128 tile, 4 waves (2x2), each wave 64x64 = 4x4 frags of 16x16x32.
__global__ __launch_bounds__(256) void k_gemm(const u16* __restrict__ A,
                                              const u16* __restrict__ W,
                                              const float* __restrict__ bias,
                                              u16* __restrict__ C) {
  __shared__ __attribute__((aligned(16))) u16 As[128 * 40];
  __shared__ __attribute__((aligned(16))) u16 Bs[128 * 40];
  int tid = threadIdx.x;
  int m0 = blockIdx.x * 128;
  int n0 = blockIdx.y * 128;
  int lane = tid & 63, wave = tid >> 6;
  int quad = lane >> 4, l15 = lane & 15;
  int wm = (wave >> 1) * 64, wn = (wave & 1) * 64;
  f32x4 acc[4][4] = {};
  for (int kc = 0; kc < 1024; kc += 32) {
#pragma unroll
    for (int i = 0; i < 2; i++) {
      int g = tid + i * 256;            // 0..511: row = g/4, kg = (g%4)*8
      int row = g >> 2, kg = (g & 3) << 3;
      *(bf16x8*)(As + row * 40 + kg) = *(const bf16x8*)(A + (size_t)(m0 + row) * 1024 + kc + kg);
      *(bf16x8*)(Bs + row * 40 + kg) = *(const bf16x8*)(W + (size_t)(n0 + row) * 1024 + kc + kg);
    }
    __syncthreads();
    bf16x8 af[4], bf[4];
#pragma unroll
    for (int mi = 0; mi < 4; mi++)
      af[mi] = *(const bf16x8*)(As + (wm + mi * 16 + l15) * 40 + quad * 8);
#pragma unroll
    for (int ni = 0; ni < 4; ni++)
      bf[ni] = *(const bf16x8*)(Bs + (wn + ni * 16 + l15) * 40 + quad * 8);
#pragma unroll
    for (int mi = 0; mi < 4; mi++)
#pragma unroll
      for (int ni = 0; ni < 4; ni++)
        acc[mi][ni] = MFMA16(af[mi], bf[ni], acc[mi][ni]);
    __syncthreads();
  }
  // C/D layout: n = lane&15 (+tile), m = quad*4 + reg (+tile)
#pragma unroll
  for (int mi = 0; mi < 4; mi++)
#pragma unroll
    for (int ni = 0; ni < 4; ni++)
#pragma unroll
      for (int r = 0; r < 4; r++) {
        int m = m0 + wm + mi * 16 + quad * 4 + r;
        int n = n0 + wn + ni * 16 + l15;
        C[(size_t)m * 3072 + n] = f2bf(acc[mi][ni][r] + bias[n]);
      }
}

// ---------- persistent GRU step kernel: all 512 timesteps, one launch ----------
// Cooperative launch, EXACTLY 256 blocks x 256 threads.
// Block = (j-group = bid>>2, mtile = bid&3). 4 waves each compute one K-quarter
// of the 3 gate matvecs; partials reduced via LDS; wave 0 runs the epilogue.
// Whh slice (48x1024) staged in LDS once. f32 h state in wave-0 registers.
// bf16 h circulates via sc1 (agent-coherent) loads/stores -> no cache fences.
//
// Barrier (v3): 4 INDEPENDENT per-mtile barriers, SINGLE-stage, LOW-contention:
//   - arrivals: monotonic relaxed RMW, 4 lines/mtile (16 arrivals/line)
//   - poll: ONLY wave0 lanes 0..3 (1 lane per line) -> no poll storm (r5 bug)
//   - release: one __syncthreads
// vs r4 (two-hop master/gen): one less MALL round trip per step.
// vs r5 (all-wave poll): 8x fewer polling lanes contending with arrivals.
//
// Ordering: arrival_t(B) happens after B's Red(t) consumption AND after B's
// sc1 h(t) stores drained (vmcnt(0) before RMW, issue-ordered at MALL).
// Poll exit at t => all 64 same-mtile blocks' h(t) visible, and their h(t-1)
// reads complete => layer-1 A/B buffer reuse (2-step separation) is safe.
// Cross-mtile: no block reads h rows outside its own mtile => per-mtile sync
// is complete.
__global__ __launch_bounds__(256) void k_steps(
    const u16* __restrict__ Whh, const float* __restrict__ bhh,
    const u16* __restrict__ gx, const float* __restrict__ h0l,
    const u16* __restrict__ hbf_init,
    u16* __restrict__ states,            // non-null (layer0): read t-1 / write t at states + t*65536
    u16* __restrict__ bufA, u16* __restrict__ bufB,   // layer1 double-buffer
    float* __restrict__ hiddens,         // layer0: [b][t][1024] f32 out, else null
    float* __restrict__ hfinal,          // [64][1024] final h (t=511)
    float* __restrict__ out2,            // optional second copy of final h
    u32* __restrict__ bar) {             // 16 lines: line L at bar[L*64]; L = mtile*4 + (jg&3)
  __shared__ __attribute__((aligned(16))) u16 Bs[48 * 1032];     // pad 1024->1032
  __shared__ __attribute__((aligned(16))) float Red[2304];       // [3 waves][3 gates][64 lanes] f32x4
  int tid = threadIdx.x;
  int lane = tid & 63, wave = tid >> 6;          // wave 0..3 = K-quarter
  int quad = lane >> 4, l15 = lane & 15;
  int bid = (int)blockIdx.x;
  int jg = bid >> 2;
  int mtile = bid & 3;
  int j0 = jg * 16;
  int j = j0 + l15;
  int kbase = wave * 256;
  u32* myline = bar + (mtile * 4 + (jg & 3)) * 64;     // this block's arrival line

  // ---- stage Whh slice: rows (gate*16 + jr), full K=1024
#pragma unroll 4
  for (int i = 0; i < 24; i++) {
    int g = tid + i * 256;                 // row = g>>7, kg = (g&127)*8
    int row = g >> 7, kg = (g & 127) << 3;
    int gate = row >> 4, jr = row & 15;
    *(bf16x8*)(Bs + row * 1032 + kg) =
        *(const bf16x8*)(Whh + (size_t)(gate * 1024 + j0 + jr) * 1024 + kg);
  }

  float br = 0.f, bz = 0.f, bn = 0.f;
  float hold[4] = {};
  u16 gvn[3][4];
  if (wave == 0) {
    br = bhh[j]; bz = bhh[1024 + j]; bn = bhh[2048 + j];
#pragma unroll
    for (int r = 0; r < 4; r++)
      hold[r] = h0l[(mtile * 16 + quad * 4 + r) * 1024 + j];
#pragma unroll
    for (int g = 0; g < 3; g++)
#pragma unroll
      for (int r = 0; r < 4; r++)
        gvn[g][r] = gx[(mtile * 16 + quad * 4 + r) * 3072 + g * 1024 + j];   // t=0
  }
  __syncthreads();

  for (int t = 0; t < 512; t++) {
    const u16* hin = (t == 0) ? hbf_init
                   : (states ? states + (size_t)(t - 1) * 65536
                             : ((t & 1) ? bufB : bufA));
    u16* hout = states ? states + (size_t)t * 65536 : ((t & 1) ? bufA : bufB);

    // coherent h load (self-draining asm) then MFMA over this wave's K-quarter
    bf16x8 a[8];
    load_h8_sc1(hin + (size_t)(mtile * 16 + l15) * 1024 + kbase + quad * 8, a);
    f32x4 acc[3] = {};
#pragma unroll
    for (int kk = 0; kk < 8; kk++) {
#pragma unroll
      for (int g = 0; g < 3; g++) {
        bf16x8 b = *(const bf16x8*)(Bs + (g * 16 + l15) * 1032 + kbase + kk * 32 + quad * 8);
        acc[g] = MFMA16(a[kk], b, acc[g]);
      }
    }
    if (wave) {
#pragma unroll
      for (int g = 0; g < 3; g++)
        *(f32x4*)(Red + (((wave - 1) * 3 + g) * 64 + lane) * 4) = acc[g];
    }
    __syncthreads();   // Red(t) ready

    if (wave == 0) {
#pragma unroll
      for (int g = 0; g < 3; g++) {
        acc[g] += *(const f32x4*)(Red + ((0 * 3 + g) * 64 + lane) * 4);
        acc[g] += *(const f32x4*)(Red + ((1 * 3 + g) * 64 + lane) * 4);
        acc[g] += *(const f32x4*)(Red + ((2 * 3 + g) * 64 + lane) * 4);
      }
#pragma unroll
      for (int r = 0; r < 4; r++) {
        int m = mtile * 16 + quad * 4 + r;
        float xr = bf2f(gvn[0][r]);
        float xz = bf2f(gvn[1][r]);
        float xn = bf2f(gvn[2][r]);
        float rg = 1.f / (1.f + __expf(-(xr + acc[0][r] + br)));
        float zg = 1.f / (1.f + __expf(-(xz + acc[1][r] + bz)));
        float nx = xn + rg * (acc[2][r] + bn);
        nx = fminf(15.f, fmaxf(-15.f, nx));
        float e2 = __expf(2.f * nx);
        float ng = (e2 - 1.f) / (e2 + 1.f);
        float hnew = (1.f - zg) * ng + zg * hold[r];
        hold[r] = hnew;
        store_h_sc1(hout + m * 1024 + j, (u32)f2bf(hnew));
      }
      // drain ONLY the sc1 h stores (hiddens deferred past arrival)
      asm volatile("s_waitcnt vmcnt(0)" ::: "memory");

      // arrival: relaxed RMW on this block's line (16 arrivals/line, monotonic)
      if (tid == 0 && t < 511)
        __hip_atomic_fetch_add(myline, 1u, __ATOMIC_RELAXED, __HIP_MEMORY_SCOPE_AGENT);

      // deferred, fire-and-forget: next-gx prefetch + hiddens + final outputs
      if (t < 511) {
        const u16* gxn = gx + (size_t)(t + 1) * 196608;
#pragma unroll
        for (int g = 0; g < 3; g++)
#pragma unroll
          for (int r = 0; r < 4; r++)
            gvn[g][r] = gxn[(mtile * 16 + quad * 4 + r) * 3072 + g * 1024 + j];
      }
      if (hiddens) {
#pragma unroll
        for (int r = 0; r < 4; r++) {
          int m = mtile * 16 + quad * 4 + r;
          __builtin_nontemporal_store(hold[r], hiddens + (size_t)m * 524288 + t * 1024 + j);
        }
      }
      if (t == 511) {
#pragma unroll
        for (int r = 0; r < 4; r++) {
          int m = mtile * 16 + quad * 4 + r;
          hfinal[m * 1024 + j] = hold[r];
          if (out2) out2[m * 1024 + j] = hold[r];
        }
      }

      // single-stage poll: wave0 lanes 0..3 watch this mtile's 4 lines
      if (t < 511 && lane < 4) {
        u32 tgt = 16u * (u32)(t + 1);
        const u32* cl = bar + (mtile * 4 + lane) * 64;
        while (__hip_atomic_load(cl, __ATOMIC_RELAXED, __HIP_MEMORY_SCOPE_AGENT) < tgt)
          __builtin_amdgcn_s_sleep(1);
      }
    }
    if (t < 511) __syncthreads();   // release waves 1..3 into step t+1
  }
}

extern "C" void kernel_launch(void* const* d_in, const int* in_sizes, int n_in,
                              void* d_out, int out_size, void* d_ws, size_t ws_size,
                              hipStream_t stream) {
  const int*   x   = (const int*)d_in[0];
  const float* h0  = (const float*)d_in[1];
  const float* emb = (const float*)d_in[2];
  const float* Wih = (const float*)d_in[3];
  const float* Whh = (const float*)d_in[4];
  const float* bih = (const float*)d_in[5];
  const float* bhh = (const float*)d_in[6];
  float* out = (float*)d_out;

  // workspace layout (total ~362 MB)
  char* ws = (char*)d_ws;
  u16* WihB = (u16*)ws;  ws += 12582912;            // [2][3072][1024] bf16
  u16* WhhB = (u16*)ws;  ws += 12582912;            // [2][3072][1024] bf16
  u16* A0   = (u16*)ws;  ws += 67108864;            // [32768][1024] bf16 (emb rows, t-major)
  u16* A1   = (u16*)ws;  ws += 67108864;            // [32768][1024] bf16 (layer-0 states)
  u16* gx   = (u16*)ws;  ws += 201326592;           // [32768][3072] bf16 (reused layer0/layer1)
  u16* h0bf = (u16*)ws;  ws += 262144;              // bf16 h0, both layers (2*65536 u16)
  u32* bar  = (u32*)ws;  ws += 262144;              // grid-barrier state (16 lines x 256B)
  u16* hbfA = (u16*)ws;  ws += 131072;              // layer-1 bf16 h double-buffer
  u16* hbfB = (u16*)ws;  ws += 131072;

  float* out_out = out;                 // [1,64,1024]
  float* hidden0 = out + 65536;         // [64,1024]
  float* hidden1 = out + 131072;        // [64,1024]
  float* hiddens = out + 196608;        // [64][512][1024]

  // per-layer stride for [L][3072][1024] weights = 3072*1024 elements
  const size_t WSTRIDE = 3145728;

  k_zero<<<8, 256, 0, stream>>>(bar);
  k_convert<<<3072, 256, 0, stream>>>(Wih, WihB, 786432);  // 6291456/8
  k_convert<<<3072, 256, 0, stream>>>(Whh, WhhB, 786432);
  k_gather<<<16384, 256, 0, stream>>>(x, emb, A0);
  k_hinit<<<256, 256, 0, stream>>>(h0, h0bf);
  k_hinit<<<256, 256, 0, stream>>>(h0 + 65536, h0bf + 65536);

  dim3 ggrid(256, 24);
  k_gemm<<<ggrid, 256, 0, stream>>>(A0, WihB, bih, gx);

  {  // layer 0: all 512 steps, one cooperative launch
    const u16*  p0 = WhhB;
    const float* p1 = bhh;
    const u16*  p2 = gx;
    const float* p3 = h0;
    const u16*  p4 = h0bf;
    u16* p5 = A1;
    u16* p6 = hbfA; u16* p7 = hbfB;
    float* p8 = hiddens; float* p9 = hidden0; float* p10 = nullptr;
    u32* p11 = bar;
    void* args[] = {&p0,&p1,&p2,&p3,&p4,&p5,&p6,&p7,&p8,&p9,&p10,&p11};
    hipLaunchCooperativeKernel((const void*)k_steps, dim3(256), dim3(256), args, 0, stream);
  }

  k_gemm<<<ggrid, 256, 0, stream>>>(A1, WihB + WSTRIDE, bih + 3072, gx);
  k_zero<<<8, 256, 0, stream>>>(bar);   // reset monotonic counters for layer 1

  {  // layer 1
    const u16*  p0 = WhhB + WSTRIDE;
    const float* p1 = bhh + 3072;
    const u16*  p2 = gx;
    const float* p3 = h0 + 65536;
    const u16*  p4 = h0bf + 65536;
    u16* p5 = nullptr;
    u16* p6 = hbfA; u16* p7 = hbfB;
    float* p8 = nullptr; float* p9 = hidden1; float* p10 = out_out;
    u32* p11 = bar;
    void* args[] = {&p0,&p1,&p2,&p3,&p4,&p5,&p6,&p7,&p8,&p9,&p10,&p11};
    hipLaunchCooperativeKernel((const void*)k_steps, dim3(256), dim3(256), args, 0, stream);
  }
}